// Round 28
// baseline (122.911 us; speedup 1.0000x reference)
//
#include <hip/hip_runtime.h>
#include <hip/hip_bf16.h>

// CVRPModel: B=16, P=200, N=2000, D=128. Inputs f32, output f32.
// Round 28: aft KSPLIT 4->8 (grid 1024 = 4 blocks/CU at (256,4); bf16 made
// registers cheap so occupancy is affordable again). partial 16.8->33.5MB.
// Everything else = round 27 (119.5 us).
// ws: sq@0 | aft_bf@1638400 | ekkT@2686976 (16.78MB) | nbf@19464192 (8.39MB)
//   | wbf@27852800 (64KB) | partial@27918336 (33.55MB, [8][16][256][256])
//   | score = partial overlap (25.6MB). total ~61.5MB.

#define BB 16
#define PP 200
#define NN 2000
#define DD 128
#define KPAD 2048
#define AST2 136   // LDS row stride (ushorts): 128+8

typedef __attribute__((ext_vector_type(8))) short short8;
typedef __attribute__((ext_vector_type(4))) float f32x4;
typedef unsigned short ushort_t;

__device__ __forceinline__ ushort_t f2bf(float x){
  union{float f; unsigned int u;} v; v.f = x;
  unsigned int r = v.u + 0x7fffu + ((v.u >> 16) & 1u);
  return (ushort_t)(r >> 16);
}
__device__ __forceinline__ float bf2f(ushort_t h){
  union{unsigned int u; float f;} v; v.u = ((unsigned int)h) << 16; return v.f;
}
// bijective chunked XCD swizzle (nwg % 8 == 0)
__device__ __forceinline__ int xcd_swz(int bid, int nwg){
  return (bid & 7) * (nwg >> 3) + (bid >> 3);
}
__device__ __forceinline__ uint4 pack8(const float x[8]){
  uint4 u;
  u.x = (unsigned int)f2bf(x[0]) | ((unsigned int)f2bf(x[1]) << 16);
  u.y = (unsigned int)f2bf(x[2]) | ((unsigned int)f2bf(x[3]) << 16);
  u.z = (unsigned int)f2bf(x[4]) | ((unsigned int)f2bf(x[5]) << 16);
  u.w = (unsigned int)f2bf(x[6]) | ((unsigned int)f2bf(x[7]) << 16);
  return u;
}

// ---------------- K1: q projections + sigmoid
__global__ __launch_bounds__(128) void k_qproj(
    const float* __restrict__ q1, const float* __restrict__ q2,
    const float* __restrict__ last, const float* __restrict__ loadv,
    const float* __restrict__ leftv, const float* __restrict__ Wq1,
    const float* __restrict__ Wq2, const float* __restrict__ Wql,
    float* __restrict__ sq_out)
{
  __shared__ float s1[8][DD], s2[8][DD], s3[8][DD];
  const int d = threadIdx.x;
  const int bp0 = blockIdx.x * 8;
  {
    const float4* g1 = (const float4*)(q1 + (size_t)bp0 * DD);
    const float4* g2 = (const float4*)(q2 + (size_t)bp0 * DD);
    const float4* g3 = (const float4*)(last + (size_t)bp0 * DD);
    float4* t1 = (float4*)&s1[0][0];
    float4* t2 = (float4*)&s2[0][0];
    float4* t3 = (float4*)&s3[0][0];
    #pragma unroll
    for (int k = 0; k < 2; k++){
      const int ii = d + k * 128;
      t1[ii] = g1[ii]; t2[ii] = g2[ii]; t3[ii] = g3[ii];
    }
  }
  __syncthreads();
  float acc[8] = {0,0,0,0,0,0,0,0};
  const float4* w1 = (const float4*)(Wq1 + (size_t)d * DD);
  const float4* w2 = (const float4*)(Wq2 + (size_t)d * DD);
  #pragma unroll 8
  for (int i = 0; i < 32; i++){
    const float4 f = w1[i];
    const int e = i * 4;
    #pragma unroll
    for (int r = 0; r < 8; r++)
      acc[r] += s1[r][e]*f.x + s1[r][e+1]*f.y + s1[r][e+2]*f.z + s1[r][e+3]*f.w;
  }
  #pragma unroll 8
  for (int i = 0; i < 32; i++){
    const float4 f = w2[i];
    const int e = i * 4;
    #pragma unroll
    for (int r = 0; r < 8; r++)
      acc[r] += s2[r][e]*f.x + s2[r][e+1]*f.y + s2[r][e+2]*f.z + s2[r][e+3]*f.w;
  }
  const float* wl = Wql + (size_t)d * (DD + 2);
  for (int e = 0; e < DD; e++){
    const float w = wl[e];
    #pragma unroll
    for (int r = 0; r < 8; r++) acc[r] += s3[r][e] * w;
  }
  const float wld = wl[DD], wlf = wl[DD+1];
  #pragma unroll
  for (int r = 0; r < 8; r++){
    const int bp = bp0 + r;
    const float qv = acc[r] + loadv[bp] * wld + leftv[bp] * wlf;
    sq_out[(size_t)bp * DD + d] = 1.f / (1.f + __expf(-qv));
  }
}

// ---------------- prep: nodes -> bf16 plane (n zero-padded) AND Wk,Wv -> bf16.
__global__ __launch_bounds__(256) void k_prep_all(
    const float* __restrict__ nodes, ushort_t* __restrict__ nbf,
    const float* __restrict__ Wk, const float* __restrict__ Wv,
    ushort_t* __restrict__ wbf)
{
  if (blockIdx.x < 2048){
    const int gid = blockIdx.x * 256 + threadIdx.x;
    const int rid = gid >> 4;
    const int d0 = (gid & 15) * 8;
    const int b = rid >> 11, n = rid & 2047;
    float x[8] = {0,0,0,0,0,0,0,0};
    if (n < NN){
      const float* src = nodes + ((size_t)b * NN + n) * DD + d0;
      const float4 v0 = *(const float4*)src;
      const float4 v1 = *(const float4*)(src + 4);
      x[0]=v0.x; x[1]=v0.y; x[2]=v0.z; x[3]=v0.w;
      x[4]=v1.x; x[5]=v1.y; x[6]=v1.z; x[7]=v1.w;
    }
    *(uint4*)(nbf + ((size_t)b * KPAD + n) * DD + d0) = pack8(x);
  } else {
    const int gid = (blockIdx.x - 2048) * 256 + threadIdx.x;
    const int flat = gid * 8;                 // 0..32767
    const float* W = (flat & 16384) ? Wv : Wk;
    const int idx = flat & 16383;
    const float4 v0 = *(const float4*)(W + idx);
    const float4 v1 = *(const float4*)(W + idx + 4);
    const float x[8] = {v0.x,v0.y,v0.z,v0.w,v1.x,v1.y,v1.z,v1.w};
    *(uint4*)(wbf + flat) = pack8(x);
  }
}

// ---------------- K2: ekkT[c][n] via MFMA (single bf16); 1D grid 256, swizzled.
__global__ __launch_bounds__(512) void k_kv_mfma(
    const ushort_t* __restrict__ nbf, const ushort_t* __restrict__ wbf,
    ushort_t* __restrict__ ekkT)
{
  extern __shared__ ushort_t st[];      // [256][136] = 69,632 B
  const int orig = xcd_swz(blockIdx.x, 16 * BB);
  const int b  = orig >> 4;
  const int n0 = (orig & 15) * 128;
  const int tid = threadIdx.x;
  const int w  = tid >> 6, l = tid & 63;
  const int wc = w >> 1;
  const int wn = w & 1;
  const int lr = l & 15;
  const int d0b = (l >> 4) * 8;

  f32x4 acc_k[2][4], acc_v[2][4];
  #pragma unroll
  for (int i = 0; i < 2; i++)
    #pragma unroll
    for (int j = 0; j < 4; j++){
      acc_k[i][j] = (f32x4){0.f,0.f,0.f,0.f};
      acc_v[i][j] = (f32x4){0.f,0.f,0.f,0.f};
    }

  #pragma unroll
  for (int kd = 0; kd < 4; kd++){
    const int d0 = kd * 32 + d0b;
    short8 ak[2], av[2];
    #pragma unroll
    for (int tf = 0; tf < 2; tf++){
      const int c = wc * 32 + tf * 16 + lr;
      const size_t wo = (size_t)c * DD + d0;
      ak[tf] = *(const short8*)(wbf + wo);
      av[tf] = *(const short8*)(wbf + 16384 + wo);
    }
    short8 bn[4];
    #pragma unroll
    for (int tn = 0; tn < 4; tn++){
      const int n = n0 + wn * 64 + tn * 16 + lr;
      bn[tn] = *(const short8*)(nbf + ((size_t)b * KPAD + n) * DD + d0);
    }
    #pragma unroll
    for (int tf = 0; tf < 2; tf++)
      #pragma unroll
      for (int tn = 0; tn < 4; tn++){
        acc_k[tf][tn] = __builtin_amdgcn_mfma_f32_16x16x32_bf16(ak[tf], bn[tn], acc_k[tf][tn], 0, 0, 0);
        acc_v[tf][tn] = __builtin_amdgcn_mfma_f32_16x16x32_bf16(av[tf], bn[tn], acc_v[tf][tn], 0, 0, 0);
      }
  }
  // epilogue: ek = exp(k), ekv = ek*v; stage rows in LDS; coalesced write.
  #pragma unroll
  for (int tf = 0; tf < 2; tf++)
    #pragma unroll
    for (int tn = 0; tn < 4; tn++)
      #pragma unroll
      for (int r = 0; r < 4; r++){
        const int row = wc * 32 + tf * 16 + (l >> 4) * 4 + r;
        const int col = wn * 64 + tn * 16 + lr;
        const float ek = __expf(acc_k[tf][tn][r]);
        st[row * 136 + col]         = f2bf(ek * acc_v[tf][tn][r]);
        st[(row + 128) * 136 + col] = f2bf(ek);
      }
  __syncthreads();
  {
    const int row = tid >> 1, seg = tid & 1;
    const uint4* src = (const uint4*)(st + row * 136 + seg * 64);
    ushort_t* dp = ekkT + ((size_t)b * 256 + row) * KPAD + n0 + seg * 64;
    uint4* dst4 = (uint4*)dp;
    #pragma unroll
    for (int j = 0; j < 8; j++) dst4[j] = src[j];
  }
}

// ---- k_aft_mfma staging registers + helpers (single bf16)
struct StageRegs { float4 dv[2][2]; float4 nv[2][2]; };

__device__ __forceinline__ void stage_load(
    const float* __restrict__ dist, const float* __restrict__ ninf,
    size_t bbase, int p0, int k0p, int tid, StageRegs& R)
{
  #pragma unroll
  for (int i = 0; i < 2; i++){
    const int flat = tid * 8 + i * 2048;
    const int pl_ = flat >> 7;
    const int kl_ = flat & 127;
    const int pg = p0 + pl_;
    const int kg = k0p + kl_;
    const bool ok = (pg < PP) && (kg + 8 <= NN);
    const size_t o = bbase + (size_t)(ok ? pg : 0) * NN + (ok ? kg : 0);
    R.dv[i][0] = *(const float4*)(dist + o);
    R.dv[i][1] = *(const float4*)(dist + o + 4);
    R.nv[i][0] = *(const float4*)(ninf + o);
    R.nv[i][1] = *(const float4*)(ninf + o + 4);
  }
}

__device__ __forceinline__ void stage_write(
    ushort_t* __restrict__ ea, float scale,
    int p0, int k0p, int tid, const StageRegs& R)
{
  #pragma unroll
  for (int i = 0; i < 2; i++){
    const int flat = tid * 8 + i * 2048;
    const int pl_ = flat >> 7;
    const int kl_ = flat & 127;
    const int pg = p0 + pl_;
    const int kg = k0p + kl_;
    const bool ok = (pg < PP) && (kg + 8 <= NN);
    float e[8];
    const float4 da = R.dv[i][0], db = R.dv[i][1];
    const float4 na = R.nv[i][0], nb = R.nv[i][1];
    e[0] = __expf(na.x - scale*da.x); e[1] = __expf(na.y - scale*da.y);
    e[2] = __expf(na.z - scale*da.z); e[3] = __expf(na.w - scale*da.w);
    e[4] = __expf(nb.x - scale*db.x); e[5] = __expf(nb.y - scale*db.y);
    e[6] = __expf(nb.z - scale*db.z); e[7] = __expf(nb.w - scale*db.w);
    if (!ok){
      #pragma unroll
      for (int j = 0; j < 8; j++) e[j] = 0.f;
    }
    *(uint4*)(ea + pl_ * AST2 + kl_) = pack8(e);
  }
}

// B-fragment set for one 32k chunk (4 x 16B)
struct BFrag { short8 h[4]; };

__device__ __forceinline__ void load_bfrag(
    const ushort_t* const bpp[4], int kg, BFrag& F)
{
  #pragma unroll
  for (int tc = 0; tc < 4; tc++)
    F.h[tc] = *(const short8*)(bpp[tc] + kg);
}

__device__ __forceinline__ void mfma_chunk(
    const ushort_t* __restrict__ ea,
    int ko, int lr, int lk, const BFrag& F, f32x4 acc[2][4])
{
  short8 ah[2];
  #pragma unroll
  for (int tp = 0; tp < 2; tp++){
    const int row = tp * 16 + lr;
    ah[tp] = *(const short8*)(ea + row * AST2 + lk + ko);
  }
  #pragma unroll
  for (int tp = 0; tp < 2; tp++)
    #pragma unroll
    for (int tc = 0; tc < 4; tc++)
      acc[tp][tc] = __builtin_amdgcn_mfma_f32_16x16x32_bf16(ah[tp], F.h[tc], acc[tp][tc], 0, 0, 0);
}

// ---------------- K3a: 2-phase e_alpha staging + 8-chunk MFMA (single bf16).
// KSPLIT=8: block covers k-slice of 256 in 2 panels of 128. Grid 1024 (4/CU).
__global__ __launch_bounds__(256, 4) void k_aft_mfma(
    const float* __restrict__ dist, const float* __restrict__ ninf,
    const ushort_t* __restrict__ ekkT,
    const float* __restrict__ log_scale, const float* __restrict__ aft_alpha,
    float* __restrict__ partial)
{
  __shared__ ushort_t ea0[32 * AST2];   // 8,704 B
  __shared__ ushort_t ea1[32 * AST2];   // 8,704 B
  const int orig = xcd_swz(blockIdx.x, 64 * BB);
  const int b  = orig >> 6;
  const int t  = orig & 63;
  const int mi = t >> 3;               // 0..7
  const int ks = t & 7;                // 0..7
  const int tid = threadIdx.x;
  const int p0 = mi * 32;
  const int k0 = ks * 256;
  const float scale = log_scale[0] * aft_alpha[0];
  const int w  = tid >> 6;
  const int l  = tid & 63;
  const int lr = l & 15;
  const int lk = (l >> 4) * 8;
  const size_t bbase = (size_t)b * PP * NN;

  f32x4 acc[2][4];
  #pragma unroll
  for (int i = 0; i < 2; i++)
    #pragma unroll
    for (int j = 0; j < 4; j++) acc[i][j] = (f32x4){0.f, 0.f, 0.f, 0.f};

  const ushort_t* bpp[4];
  #pragma unroll
  for (int tc = 0; tc < 4; tc++){
    const int c = w * 64 + tc * 16 + lr;
    bpp[tc] = ekkT + ((size_t)b * 256 + c) * KPAD + k0 + lk;
  }

  BFrag FA, FB;
  StageRegs R;

  // prologue: stage panel 0 -> buf0; first B chunk in flight
  stage_load(dist, ninf, bbase, p0, k0, tid, R);
  stage_write(ea0, scale, p0, k0, tid, R);
  load_bfrag(bpp, 0, FA);
  __syncthreads();

  // ---- phase 0 (buf0, kg 0..96); prefetch next stage early
  stage_load(dist, ninf, bbase, p0, k0 + 128, tid, R);
  load_bfrag(bpp, 32, FB);  mfma_chunk(ea0, 0,  lr, lk, FA, acc);
  load_bfrag(bpp, 64, FA);  mfma_chunk(ea0, 32, lr, lk, FB, acc);
  load_bfrag(bpp, 96, FB);  mfma_chunk(ea0, 64, lr, lk, FA, acc);
  load_bfrag(bpp, 128, FA); mfma_chunk(ea0, 96, lr, lk, FB, acc);
  __syncthreads();
  stage_write(ea1, scale, p0, k0 + 128, tid, R);
  __syncthreads();

  // ---- phase 1 (buf1, kg 128..224)
  load_bfrag(bpp, 160, FB); mfma_chunk(ea1, 0,  lr, lk, FA, acc);
  load_bfrag(bpp, 192, FA); mfma_chunk(ea1, 32, lr, lk, FB, acc);
  load_bfrag(bpp, 224, FB); mfma_chunk(ea1, 64, lr, lk, FA, acc);
                            mfma_chunk(ea1, 96, lr, lk, FB, acc);

  // ---- store
  #pragma unroll
  for (int tp = 0; tp < 2; tp++){
    const int prow = p0 + tp * 16 + (l >> 4) * 4;
    #pragma unroll
    for (int tc = 0; tc < 4; tc++){
      const int c = w * 64 + tc * 16 + (l & 15);
      #pragma unroll
      for (int r = 0; r < 4; r++){
        partial[(size_t)ks * 1048576 + ((size_t)b * 256 + prow + r) * 256 + c] = acc[tp][tc][r];
      }
    }
  }
}

// ---------------- K3b: reduce 8 partials; aft = sq*bias/(den+eps) -> bf16
__global__ __launch_bounds__(256) void k_aft_reduce(
    const float* __restrict__ partial, const float* __restrict__ sq,
    ushort_t* __restrict__ aft_bf)
{
  const int pl = threadIdx.x >> 7;
  const int c  = threadIdx.x & 127;
  const int b = blockIdx.y;
  #pragma unroll
  for (int i = 0; i < 4; i++){
    const int p = blockIdx.x * 8 + i * 2 + pl;   // 0..255
    float v = 0.f;
    if (p < PP){
      const size_t base = ((size_t)b * 256 + p) * 256;
      float bias = 0.f, den = 0.f;
      #pragma unroll
      for (int ksi = 0; ksi < 8; ksi++){
        const float* ptr = partial + (size_t)ksi * 1048576 + base;
        bias += ptr[c];
        den  += ptr[c + 128];
      }
      v = sq[((size_t)b * PP + p) * DD + c] * (bias / (den + 1e-20f));
    }
    aft_bf[((size_t)b * 256 + p) * DD + c] = f2bf(v);
  }
}

// ---------------- K4a: pure score GEMM (single bf16, raw dots, f32 store).
__global__ __launch_bounds__(512) void k_score_gemm(
    const ushort_t* __restrict__ aft_bf, const ushort_t* __restrict__ nbf,
    float* __restrict__ score_out)
{
  const int orig = xcd_swz(blockIdx.x, 32 * BB);
  const int b  = orig >> 5;
  const int t  = orig & 31;
  const int mi = t >> 3;              // 0..3
  const int nt = t & 7;               // 0..7
  const int tid = threadIdx.x;
  const int p0 = mi * 64;
  const int n0 = nt * 256;
  const int w  = tid >> 6, l = tid & 63;
  const int wp = w >> 2, wc = w & 3;
  const int lr = l & 15, lk = (l >> 4) * 8;

  f32x4 acc[2][4];
  #pragma unroll
  for (int i = 0; i < 2; i++)
    #pragma unroll
    for (int j = 0; j < 4; j++) acc[i][j] = (f32x4){0.f, 0.f, 0.f, 0.f};

  const ushort_t* ap[2];
  #pragma unroll
  for (int tp = 0; tp < 2; tp++){
    const int row = p0 + wp * 32 + tp * 16 + lr;
    ap[tp] = aft_bf + ((size_t)b * 256 + row) * DD + lk;
  }
  const ushort_t* bp[4];
  #pragma unroll
  for (int tc = 0; tc < 4; tc++){
    const int n = n0 + wc * 64 + tc * 16 + lr;
    bp[tc] = nbf + ((size_t)b * KPAD + n) * DD + lk;
  }

  #pragma unroll
  for (int kc = 0; kc < 4; kc++){
    const int ko = kc * 32;
    short8 a[2], bb[4];
    #pragma unroll
    for (int tp = 0; tp < 2; tp++)
      a[tp] = *(const short8*)(ap[tp] + ko);
    #pragma unroll
    for (int tc = 0; tc < 4; tc++)
      bb[tc] = *(const short8*)(bp[tc] + ko);
    #pragma unroll
    for (int tp = 0; tp < 2; tp++)
      #pragma unroll
      for (int tc = 0; tc < 4; tc++)
        acc[tp][tc] = __builtin_amdgcn_mfma_f32_16x16x32_bf16(a[tp], bb[tc], acc[tp][tc], 0, 0, 0);
  }
  // store raw dots
  #pragma unroll
  for (int tp = 0; tp < 2; tp++){
    #pragma unroll
    for (int r = 0; r < 4; r++){
      const int p = p0 + wp * 32 + tp * 16 + (l >> 4) * 4 + r;
      if (p < PP){
        #pragma unroll
        for (int tc = 0; tc < 4; tc++){
          const int ncol = n0 + wc * 64 + tc * 16 + (l & 15);
          if (ncol < NN)
            score_out[((size_t)b * PP + p) * NN + ncol] = acc[tp][tc][r];
        }
      }
    }
  }
}

// ---------------- K4b: fused epilogue + softmax. One (b,p) row per block.
// e = exp(10*tanh(sc) + nf - 10) = exp(nf - 20/(E+1)), E = exp(2*sc).
__global__ __launch_bounds__(256) void k_scale_fused(
    const float* __restrict__ score, const float* __restrict__ dist,
    const float* __restrict__ ninf, const float* __restrict__ log_scale,
    const float* __restrict__ probs_alpha, float* __restrict__ out)
{
  __shared__ float e_s[NN];           // 8000 B
  __shared__ float red[256];
  const int tid = threadIdx.x;
  const int p = blockIdx.x;
  const int b = blockIdx.y;
  const float spb = log_scale[0] * probs_alpha[0];
  const float isd = 0.088388347648318447f;  // 1/sqrt(128)
  const size_t base = ((size_t)b * PP + p) * NN;
  const float4* s4 = (const float4*)(score + base);
  const float4* d4 = (const float4*)(dist + base);
  const float4* n4 = (const float4*)(ninf + base);
  float4* es4 = (float4*)e_s;
  float psum = 0.f;
  for (int i = tid; i < NN / 4; i += 256){
    const float4 s = s4[i];
    const float4 d = d4[i];
    const float4 nf = n4[i];
    float4 e;
    {
      const float E0 = __expf(2.f * (s.x * isd - spb * d.x));
      const float E1 = __expf(2.f * (s.y * isd - spb * d.y));
      const float E2 = __expf(2.f * (s.z * isd - spb * d.z));
      const float E3 = __expf(2.f * (s.w * isd - spb * d.w));
      e.x = __expf(nf.x - 20.f / (E0 + 1.f));
      e.y = __expf(nf.y - 20.f / (E1 + 1.f));
      e.z = __expf(nf.z - 20.f / (E2 + 1.f));
      e.w = __expf(nf.w - 20.f / (E3 + 1.f));
    }
    es4[i] = e;
    psum += e.x + e.y + e.z + e.w;
  }
  red[tid] = psum;
  __syncthreads();
  for (int st = 128; st > 0; st >>= 1){
    if (tid < st) red[tid] += red[tid + st];
    __syncthreads();
  }
  const float inv = 1.f / red[0];
  float4* o4 = (float4*)(out + base);
  for (int i = tid; i < NN / 4; i += 256){
    float4 v = es4[i];
    v.x *= inv; v.y *= inv; v.z *= inv; v.w *= inv;
    o4[i] = v;
  }
}

extern "C" void kernel_launch(void* const* d_in, const int* in_sizes, int n_in,
                              void* d_out, int out_size, void* d_ws, size_t ws_size,
                              hipStream_t stream)
{
  const float* nodes = (const float*)d_in[0];
  const float* last  = (const float*)d_in[1];
  const float* q1    = (const float*)d_in[2];
  const float* q2    = (const float*)d_in[3];
  const float* loadv = (const float*)d_in[4];
  const float* leftv = (const float*)d_in[5];
  const float* dist  = (const float*)d_in[6];
  const float* ninf  = (const float*)d_in[7];
  const float* ls    = (const float*)d_in[8];
  const float* Wq1   = (const float*)d_in[9];
  const float* Wq2   = (const float*)d_in[10];
  const float* Wql   = (const float*)d_in[11];
  const float* Wk    = (const float*)d_in[12];
  const float* Wv    = (const float*)d_in[13];
  const float* aa    = (const float*)d_in[14];
  const float* pa    = (const float*)d_in[15];
  float* out = (float*)d_out;

  char* wsb = (char*)d_ws;
  float*    sq      = (float*)(wsb);                 // 1,638,400 B
  ushort_t* aft_bf  = (ushort_t*)(wsb + 1638400);    // 1,048,576 B
  ushort_t* ekkT    = (ushort_t*)(wsb + 2686976);    // 16,777,216 B [16][256][2048]
  ushort_t* nbf     = (ushort_t*)(wsb + 19464192);   //  8,388,608 B [16][2048][128]
  ushort_t* wbf     = (ushort_t*)(wsb + 27852800);   //     65,536 B [2][128][128]
  float*    partial = (float*)(wsb + 27918336);      // 33,554,432 B [8][16][256][256]
  float*    score   = partial;                       // 25,600,000 B (partial dead)

  k_qproj<<<dim3((BB * PP) / 8), dim3(128), 0, stream>>>(q1, q2, last, loadv, leftv, Wq1, Wq2, Wql, sq);
  k_prep_all<<<dim3(2064), dim3(256), 0, stream>>>(nodes, nbf, Wk, Wv, wbf);
  k_kv_mfma<<<dim3(16 * BB), dim3(512), 69632, stream>>>(nbf, wbf, ekkT);
  k_aft_mfma<<<dim3(64 * BB), dim3(256), 0, stream>>>(dist, ninf, ekkT, ls, aa, partial);
  k_aft_reduce<<<dim3(32, BB), dim3(256), 0, stream>>>(partial, sq, aft_bf);
  k_score_gemm<<<dim3(32 * BB), dim3(512), 0, stream>>>(aft_bf, nbf, score);
  k_scale_fused<<<dim3(PP, BB), dim3(256), 0, stream>>>(score, dist, ninf, ls, pa, out);
}

// Round 29
// 119.356 us; speedup vs baseline: 1.0298x; 1.0298x over previous
//
#include <hip/hip_runtime.h>
#include <hip/hip_bf16.h>

// CVRPModel: B=16, P=200, N=2000, D=128. Inputs f32, output f32.
// Round 29: revert to round-27 exact configuration (KSPLIT=4, grid 512,
// (256,2), partial 16.8MB) — measured best 119.5 us. Round-28 KSPLIT=8
// regressed (+3.4: doubled partial writes > latency-hiding gain).
// ws (bytes): sq@0 1.64MB | aft_bf@1638400 1.05MB | ekkT@2686976 16.78MB |
//   nbf@19464192 8.39MB | wbf@27852800 64KB | partial@27918336 16.78MB
//   | score = partial overlap (25.6MB). total ~53.5MB.

#define BB 16
#define PP 200
#define NN 2000
#define DD 128
#define KPAD 2048
#define AST2 136   // LDS row stride (ushorts): 128+8

typedef __attribute__((ext_vector_type(8))) short short8;
typedef __attribute__((ext_vector_type(4))) float f32x4;
typedef unsigned short ushort_t;

__device__ __forceinline__ ushort_t f2bf(float x){
  union{float f; unsigned int u;} v; v.f = x;
  unsigned int r = v.u + 0x7fffu + ((v.u >> 16) & 1u);
  return (ushort_t)(r >> 16);
}
__device__ __forceinline__ float bf2f(ushort_t h){
  union{unsigned int u; float f;} v; v.u = ((unsigned int)h) << 16; return v.f;
}
// bijective chunked XCD swizzle (nwg % 8 == 0)
__device__ __forceinline__ int xcd_swz(int bid, int nwg){
  return (bid & 7) * (nwg >> 3) + (bid >> 3);
}
__device__ __forceinline__ uint4 pack8(const float x[8]){
  uint4 u;
  u.x = (unsigned int)f2bf(x[0]) | ((unsigned int)f2bf(x[1]) << 16);
  u.y = (unsigned int)f2bf(x[2]) | ((unsigned int)f2bf(x[3]) << 16);
  u.z = (unsigned int)f2bf(x[4]) | ((unsigned int)f2bf(x[5]) << 16);
  u.w = (unsigned int)f2bf(x[6]) | ((unsigned int)f2bf(x[7]) << 16);
  return u;
}

// ---------------- K1: q projections + sigmoid
__global__ __launch_bounds__(128) void k_qproj(
    const float* __restrict__ q1, const float* __restrict__ q2,
    const float* __restrict__ last, const float* __restrict__ loadv,
    const float* __restrict__ leftv, const float* __restrict__ Wq1,
    const float* __restrict__ Wq2, const float* __restrict__ Wql,
    float* __restrict__ sq_out)
{
  __shared__ float s1[8][DD], s2[8][DD], s3[8][DD];
  const int d = threadIdx.x;
  const int bp0 = blockIdx.x * 8;
  {
    const float4* g1 = (const float4*)(q1 + (size_t)bp0 * DD);
    const float4* g2 = (const float4*)(q2 + (size_t)bp0 * DD);
    const float4* g3 = (const float4*)(last + (size_t)bp0 * DD);
    float4* t1 = (float4*)&s1[0][0];
    float4* t2 = (float4*)&s2[0][0];
    float4* t3 = (float4*)&s3[0][0];
    #pragma unroll
    for (int k = 0; k < 2; k++){
      const int ii = d + k * 128;
      t1[ii] = g1[ii]; t2[ii] = g2[ii]; t3[ii] = g3[ii];
    }
  }
  __syncthreads();
  float acc[8] = {0,0,0,0,0,0,0,0};
  const float4* w1 = (const float4*)(Wq1 + (size_t)d * DD);
  const float4* w2 = (const float4*)(Wq2 + (size_t)d * DD);
  #pragma unroll 8
  for (int i = 0; i < 32; i++){
    const float4 f = w1[i];
    const int e = i * 4;
    #pragma unroll
    for (int r = 0; r < 8; r++)
      acc[r] += s1[r][e]*f.x + s1[r][e+1]*f.y + s1[r][e+2]*f.z + s1[r][e+3]*f.w;
  }
  #pragma unroll 8
  for (int i = 0; i < 32; i++){
    const float4 f = w2[i];
    const int e = i * 4;
    #pragma unroll
    for (int r = 0; r < 8; r++)
      acc[r] += s2[r][e]*f.x + s2[r][e+1]*f.y + s2[r][e+2]*f.z + s2[r][e+3]*f.w;
  }
  const float* wl = Wql + (size_t)d * (DD + 2);
  for (int e = 0; e < DD; e++){
    const float w = wl[e];
    #pragma unroll
    for (int r = 0; r < 8; r++) acc[r] += s3[r][e] * w;
  }
  const float wld = wl[DD], wlf = wl[DD+1];
  #pragma unroll
  for (int r = 0; r < 8; r++){
    const int bp = bp0 + r;
    const float qv = acc[r] + loadv[bp] * wld + leftv[bp] * wlf;
    sq_out[(size_t)bp * DD + d] = 1.f / (1.f + __expf(-qv));
  }
}

// ---------------- prep: nodes -> bf16 plane (n zero-padded) AND Wk,Wv -> bf16.
__global__ __launch_bounds__(256) void k_prep_all(
    const float* __restrict__ nodes, ushort_t* __restrict__ nbf,
    const float* __restrict__ Wk, const float* __restrict__ Wv,
    ushort_t* __restrict__ wbf)
{
  if (blockIdx.x < 2048){
    const int gid = blockIdx.x * 256 + threadIdx.x;
    const int rid = gid >> 4;
    const int d0 = (gid & 15) * 8;
    const int b = rid >> 11, n = rid & 2047;
    float x[8] = {0,0,0,0,0,0,0,0};
    if (n < NN){
      const float* src = nodes + ((size_t)b * NN + n) * DD + d0;
      const float4 v0 = *(const float4*)src;
      const float4 v1 = *(const float4*)(src + 4);
      x[0]=v0.x; x[1]=v0.y; x[2]=v0.z; x[3]=v0.w;
      x[4]=v1.x; x[5]=v1.y; x[6]=v1.z; x[7]=v1.w;
    }
    *(uint4*)(nbf + ((size_t)b * KPAD + n) * DD + d0) = pack8(x);
  } else {
    const int gid = (blockIdx.x - 2048) * 256 + threadIdx.x;
    const int flat = gid * 8;                 // 0..32767
    const float* W = (flat & 16384) ? Wv : Wk;
    const int idx = flat & 16383;
    const float4 v0 = *(const float4*)(W + idx);
    const float4 v1 = *(const float4*)(W + idx + 4);
    const float x[8] = {v0.x,v0.y,v0.z,v0.w,v1.x,v1.y,v1.z,v1.w};
    *(uint4*)(wbf + flat) = pack8(x);
  }
}

// ---------------- K2: ekkT[c][n] via MFMA (single bf16); 1D grid 256, swizzled.
__global__ __launch_bounds__(512) void k_kv_mfma(
    const ushort_t* __restrict__ nbf, const ushort_t* __restrict__ wbf,
    ushort_t* __restrict__ ekkT)
{
  extern __shared__ ushort_t st[];      // [256][136] = 69,632 B
  const int orig = xcd_swz(blockIdx.x, 16 * BB);
  const int b  = orig >> 4;
  const int n0 = (orig & 15) * 128;
  const int tid = threadIdx.x;
  const int w  = tid >> 6, l = tid & 63;
  const int wc = w >> 1;
  const int wn = w & 1;
  const int lr = l & 15;
  const int d0b = (l >> 4) * 8;

  f32x4 acc_k[2][4], acc_v[2][4];
  #pragma unroll
  for (int i = 0; i < 2; i++)
    #pragma unroll
    for (int j = 0; j < 4; j++){
      acc_k[i][j] = (f32x4){0.f,0.f,0.f,0.f};
      acc_v[i][j] = (f32x4){0.f,0.f,0.f,0.f};
    }

  #pragma unroll
  for (int kd = 0; kd < 4; kd++){
    const int d0 = kd * 32 + d0b;
    short8 ak[2], av[2];
    #pragma unroll
    for (int tf = 0; tf < 2; tf++){
      const int c = wc * 32 + tf * 16 + lr;
      const size_t wo = (size_t)c * DD + d0;
      ak[tf] = *(const short8*)(wbf + wo);
      av[tf] = *(const short8*)(wbf + 16384 + wo);
    }
    short8 bn[4];
    #pragma unroll
    for (int tn = 0; tn < 4; tn++){
      const int n = n0 + wn * 64 + tn * 16 + lr;
      bn[tn] = *(const short8*)(nbf + ((size_t)b * KPAD + n) * DD + d0);
    }
    #pragma unroll
    for (int tf = 0; tf < 2; tf++)
      #pragma unroll
      for (int tn = 0; tn < 4; tn++){
        acc_k[tf][tn] = __builtin_amdgcn_mfma_f32_16x16x32_bf16(ak[tf], bn[tn], acc_k[tf][tn], 0, 0, 0);
        acc_v[tf][tn] = __builtin_amdgcn_mfma_f32_16x16x32_bf16(av[tf], bn[tn], acc_v[tf][tn], 0, 0, 0);
      }
  }
  // epilogue: ek = exp(k), ekv = ek*v; stage rows in LDS; coalesced write.
  #pragma unroll
  for (int tf = 0; tf < 2; tf++)
    #pragma unroll
    for (int tn = 0; tn < 4; tn++)
      #pragma unroll
      for (int r = 0; r < 4; r++){
        const int row = wc * 32 + tf * 16 + (l >> 4) * 4 + r;
        const int col = wn * 64 + tn * 16 + lr;
        const float ek = __expf(acc_k[tf][tn][r]);
        st[row * 136 + col]         = f2bf(ek * acc_v[tf][tn][r]);
        st[(row + 128) * 136 + col] = f2bf(ek);
      }
  __syncthreads();
  {
    const int row = tid >> 1, seg = tid & 1;
    const uint4* src = (const uint4*)(st + row * 136 + seg * 64);
    ushort_t* dp = ekkT + ((size_t)b * 256 + row) * KPAD + n0 + seg * 64;
    uint4* dst4 = (uint4*)dp;
    #pragma unroll
    for (int j = 0; j < 8; j++) dst4[j] = src[j];
  }
}

// ---- k_aft_mfma staging registers + helpers (single bf16)
struct StageRegs { float4 dv[2][2]; float4 nv[2][2]; };

__device__ __forceinline__ void stage_load(
    const float* __restrict__ dist, const float* __restrict__ ninf,
    size_t bbase, int p0, int k0p, int tid, StageRegs& R)
{
  #pragma unroll
  for (int i = 0; i < 2; i++){
    const int flat = tid * 8 + i * 2048;
    const int pl_ = flat >> 7;
    const int kl_ = flat & 127;
    const int pg = p0 + pl_;
    const int kg = k0p + kl_;
    const bool ok = (pg < PP) && (kg + 8 <= NN);
    const size_t o = bbase + (size_t)(ok ? pg : 0) * NN + (ok ? kg : 0);
    R.dv[i][0] = *(const float4*)(dist + o);
    R.dv[i][1] = *(const float4*)(dist + o + 4);
    R.nv[i][0] = *(const float4*)(ninf + o);
    R.nv[i][1] = *(const float4*)(ninf + o + 4);
  }
}

__device__ __forceinline__ void stage_write(
    ushort_t* __restrict__ ea, float scale,
    int p0, int k0p, int tid, const StageRegs& R)
{
  #pragma unroll
  for (int i = 0; i < 2; i++){
    const int flat = tid * 8 + i * 2048;
    const int pl_ = flat >> 7;
    const int kl_ = flat & 127;
    const int pg = p0 + pl_;
    const int kg = k0p + kl_;
    const bool ok = (pg < PP) && (kg + 8 <= NN);
    float e[8];
    const float4 da = R.dv[i][0], db = R.dv[i][1];
    const float4 na = R.nv[i][0], nb = R.nv[i][1];
    e[0] = __expf(na.x - scale*da.x); e[1] = __expf(na.y - scale*da.y);
    e[2] = __expf(na.z - scale*da.z); e[3] = __expf(na.w - scale*da.w);
    e[4] = __expf(nb.x - scale*db.x); e[5] = __expf(nb.y - scale*db.y);
    e[6] = __expf(nb.z - scale*db.z); e[7] = __expf(nb.w - scale*db.w);
    if (!ok){
      #pragma unroll
      for (int j = 0; j < 8; j++) e[j] = 0.f;
    }
    *(uint4*)(ea + pl_ * AST2 + kl_) = pack8(e);
  }
}

// B-fragment set for one 32k chunk (4 x 16B)
struct BFrag { short8 h[4]; };

__device__ __forceinline__ void load_bfrag(
    const ushort_t* const bpp[4], int kg, BFrag& F)
{
  #pragma unroll
  for (int tc = 0; tc < 4; tc++)
    F.h[tc] = *(const short8*)(bpp[tc] + kg);
}

__device__ __forceinline__ void mfma_chunk(
    const ushort_t* __restrict__ ea,
    int ko, int lr, int lk, const BFrag& F, f32x4 acc[2][4])
{
  short8 ah[2];
  #pragma unroll
  for (int tp = 0; tp < 2; tp++){
    const int row = tp * 16 + lr;
    ah[tp] = *(const short8*)(ea + row * AST2 + lk + ko);
  }
  #pragma unroll
  for (int tp = 0; tp < 2; tp++)
    #pragma unroll
    for (int tc = 0; tc < 4; tc++)
      acc[tp][tc] = __builtin_amdgcn_mfma_f32_16x16x32_bf16(ah[tp], F.h[tc], acc[tp][tc], 0, 0, 0);
}

// ---------------- K3a: 4-phase e_alpha staging + 16-chunk MFMA (single bf16).
__global__ __launch_bounds__(256, 2) void k_aft_mfma(
    const float* __restrict__ dist, const float* __restrict__ ninf,
    const ushort_t* __restrict__ ekkT,
    const float* __restrict__ log_scale, const float* __restrict__ aft_alpha,
    float* __restrict__ partial)
{
  __shared__ ushort_t ea0[32 * AST2];   // 8,704 B
  __shared__ ushort_t ea1[32 * AST2];   // 8,704 B
  const int orig = xcd_swz(blockIdx.x, 32 * BB);
  const int b  = orig >> 5;
  const int t  = orig & 31;
  const int mi = t >> 2;
  const int ks = t & 3;
  const int tid = threadIdx.x;
  const int p0 = mi * 32;
  const int k0 = ks * 512;
  const float scale = log_scale[0] * aft_alpha[0];
  const int w  = tid >> 6;
  const int l  = tid & 63;
  const int lr = l & 15;
  const int lk = (l >> 4) * 8;
  const size_t bbase = (size_t)b * PP * NN;

  f32x4 acc[2][4];
  #pragma unroll
  for (int i = 0; i < 2; i++)
    #pragma unroll
    for (int j = 0; j < 4; j++) acc[i][j] = (f32x4){0.f, 0.f, 0.f, 0.f};

  const ushort_t* bpp[4];
  #pragma unroll
  for (int tc = 0; tc < 4; tc++){
    const int c = w * 64 + tc * 16 + lr;
    bpp[tc] = ekkT + ((size_t)b * 256 + c) * KPAD + k0 + lk;
  }

  BFrag FA, FB;
  StageRegs R;

  // prologue: stage panel 0 -> buf0; first B chunk in flight
  stage_load(dist, ninf, bbase, p0, k0, tid, R);
  stage_write(ea0, scale, p0, k0, tid, R);
  load_bfrag(bpp, 0, FA);
  __syncthreads();

  // ---- phase 0 (buf0, kg 0..96); prefetch next stage early
  stage_load(dist, ninf, bbase, p0, k0 + 128, tid, R);
  load_bfrag(bpp, 32, FB);  mfma_chunk(ea0, 0,  lr, lk, FA, acc);
  load_bfrag(bpp, 64, FA);  mfma_chunk(ea0, 32, lr, lk, FB, acc);
  load_bfrag(bpp, 96, FB);  mfma_chunk(ea0, 64, lr, lk, FA, acc);
  load_bfrag(bpp, 128, FA); mfma_chunk(ea0, 96, lr, lk, FB, acc);
  __syncthreads();
  stage_write(ea1, scale, p0, k0 + 128, tid, R);
  __syncthreads();

  // ---- phase 1 (buf1, kg 128..224)
  stage_load(dist, ninf, bbase, p0, k0 + 256, tid, R);
  load_bfrag(bpp, 160, FB); mfma_chunk(ea1, 0,  lr, lk, FA, acc);
  load_bfrag(bpp, 192, FA); mfma_chunk(ea1, 32, lr, lk, FB, acc);
  load_bfrag(bpp, 224, FB); mfma_chunk(ea1, 64, lr, lk, FA, acc);
  load_bfrag(bpp, 256, FA); mfma_chunk(ea1, 96, lr, lk, FB, acc);
  __syncthreads();
  stage_write(ea0, scale, p0, k0 + 256, tid, R);
  __syncthreads();

  // ---- phase 2 (buf0, kg 256..352)
  stage_load(dist, ninf, bbase, p0, k0 + 384, tid, R);
  load_bfrag(bpp, 288, FB); mfma_chunk(ea0, 0,  lr, lk, FA, acc);
  load_bfrag(bpp, 320, FA); mfma_chunk(ea0, 32, lr, lk, FB, acc);
  load_bfrag(bpp, 352, FB); mfma_chunk(ea0, 64, lr, lk, FA, acc);
  load_bfrag(bpp, 384, FA); mfma_chunk(ea0, 96, lr, lk, FB, acc);
  __syncthreads();
  stage_write(ea1, scale, p0, k0 + 384, tid, R);
  __syncthreads();

  // ---- phase 3 (buf1, kg 384..480)
  load_bfrag(bpp, 416, FB); mfma_chunk(ea1, 0,  lr, lk, FA, acc);
  load_bfrag(bpp, 448, FA); mfma_chunk(ea1, 32, lr, lk, FB, acc);
  load_bfrag(bpp, 480, FB); mfma_chunk(ea1, 64, lr, lk, FA, acc);
                            mfma_chunk(ea1, 96, lr, lk, FB, acc);

  // ---- store
  #pragma unroll
  for (int tp = 0; tp < 2; tp++){
    const int prow = p0 + tp * 16 + (l >> 4) * 4;
    #pragma unroll
    for (int tc = 0; tc < 4; tc++){
      const int c = w * 64 + tc * 16 + (l & 15);
      #pragma unroll
      for (int r = 0; r < 4; r++){
        partial[(size_t)ks * 1048576 + ((size_t)b * 256 + prow + r) * 256 + c] = acc[tp][tc][r];
      }
    }
  }
}

// ---------------- K3b: reduce 4 partials; aft = sq*bias/(den+eps) -> bf16
__global__ __launch_bounds__(256) void k_aft_reduce(
    const float* __restrict__ partial, const float* __restrict__ sq,
    ushort_t* __restrict__ aft_bf)
{
  const int pl = threadIdx.x >> 7;
  const int c  = threadIdx.x & 127;
  const int b = blockIdx.y;
  #pragma unroll
  for (int i = 0; i < 4; i++){
    const int p = blockIdx.x * 8 + i * 2 + pl;   // 0..255
    float v = 0.f;
    if (p < PP){
      const size_t base = ((size_t)b * 256 + p) * 256;
      float bias = 0.f, den = 0.f;
      #pragma unroll
      for (int ksi = 0; ksi < 4; ksi++){
        const float* ptr = partial + (size_t)ksi * 1048576 + base;
        bias += ptr[c];
        den  += ptr[c + 128];
      }
      v = sq[((size_t)b * PP + p) * DD + c] * (bias / (den + 1e-20f));
    }
    aft_bf[((size_t)b * 256 + p) * DD + c] = f2bf(v);
  }
}

// ---------------- K4a: pure score GEMM (single bf16, raw dots, f32 store).
__global__ __launch_bounds__(512) void k_score_gemm(
    const ushort_t* __restrict__ aft_bf, const ushort_t* __restrict__ nbf,
    float* __restrict__ score_out)
{
  const int orig = xcd_swz(blockIdx.x, 32 * BB);
  const int b  = orig >> 5;
  const int t  = orig & 31;
  const int mi = t >> 3;              // 0..3
  const int nt = t & 7;               // 0..7
  const int tid = threadIdx.x;
  const int p0 = mi * 64;
  const int n0 = nt * 256;
  const int w  = tid >> 6, l = tid & 63;
  const int wp = w >> 2, wc = w & 3;
  const int lr = l & 15, lk = (l >> 4) * 8;

  f32x4 acc[2][4];
  #pragma unroll
  for (int i = 0; i < 2; i++)
    #pragma unroll
    for (int j = 0; j < 4; j++) acc[i][j] = (f32x4){0.f, 0.f, 0.f, 0.f};

  const ushort_t* ap[2];
  #pragma unroll
  for (int tp = 0; tp < 2; tp++){
    const int row = p0 + wp * 32 + tp * 16 + lr;
    ap[tp] = aft_bf + ((size_t)b * 256 + row) * DD + lk;
  }
  const ushort_t* bp[4];
  #pragma unroll
  for (int tc = 0; tc < 4; tc++){
    const int n = n0 + wc * 64 + tc * 16 + lr;
    bp[tc] = nbf + ((size_t)b * KPAD + n) * DD + lk;
  }

  #pragma unroll
  for (int kc = 0; kc < 4; kc++){
    const int ko = kc * 32;
    short8 a[2], bb[4];
    #pragma unroll
    for (int tp = 0; tp < 2; tp++)
      a[tp] = *(const short8*)(ap[tp] + ko);
    #pragma unroll
    for (int tc = 0; tc < 4; tc++)
      bb[tc] = *(const short8*)(bp[tc] + ko);
    #pragma unroll
    for (int tp = 0; tp < 2; tp++)
      #pragma unroll
      for (int tc = 0; tc < 4; tc++)
        acc[tp][tc] = __builtin_amdgcn_mfma_f32_16x16x32_bf16(a[tp], bb[tc], acc[tp][tc], 0, 0, 0);
  }
  // store raw dots
  #pragma unroll
  for (int tp = 0; tp < 2; tp++){
    #pragma unroll
    for (int r = 0; r < 4; r++){
      const int p = p0 + wp * 32 + tp * 16 + (l >> 4) * 4 + r;
      if (p < PP){
        #pragma unroll
        for (int tc = 0; tc < 4; tc++){
          const int ncol = n0 + wc * 64 + tc * 16 + (l & 15);
          if (ncol < NN)
            score_out[((size_t)b * PP + p) * NN + ncol] = acc[tp][tc][r];
        }
      }
    }
  }
}

// ---------------- K4b: fused epilogue + softmax. One (b,p) row per block.
// e = exp(10*tanh(sc) + nf - 10) = exp(nf - 20/(E+1)), E = exp(2*sc).
__global__ __launch_bounds__(256) void k_scale_fused(
    const float* __restrict__ score, const float* __restrict__ dist,
    const float* __restrict__ ninf, const float* __restrict__ log_scale,
    const float* __restrict__ probs_alpha, float* __restrict__ out)
{
  __shared__ float e_s[NN];           // 8000 B
  __shared__ float red[256];
  const int tid = threadIdx.x;
  const int p = blockIdx.x;
  const int b = blockIdx.y;
  const float spb = log_scale[0] * probs_alpha[0];
  const float isd = 0.088388347648318447f;  // 1/sqrt(128)
  const size_t base = ((size_t)b * PP + p) * NN;
  const float4* s4 = (const float4*)(score + base);
  const float4* d4 = (const float4*)(dist + base);
  const float4* n4 = (const float4*)(ninf + base);
  float4* es4 = (float4*)e_s;
  float psum = 0.f;
  for (int i = tid; i < NN / 4; i += 256){
    const float4 s = s4[i];
    const float4 d = d4[i];
    const float4 nf = n4[i];
    float4 e;
    {
      const float E0 = __expf(2.f * (s.x * isd - spb * d.x));
      const float E1 = __expf(2.f * (s.y * isd - spb * d.y));
      const float E2 = __expf(2.f * (s.z * isd - spb * d.z));
      const float E3 = __expf(2.f * (s.w * isd - spb * d.w));
      e.x = __expf(nf.x - 20.f / (E0 + 1.f));
      e.y = __expf(nf.y - 20.f / (E1 + 1.f));
      e.z = __expf(nf.z - 20.f / (E2 + 1.f));
      e.w = __expf(nf.w - 20.f / (E3 + 1.f));
    }
    es4[i] = e;
    psum += e.x + e.y + e.z + e.w;
  }
  red[tid] = psum;
  __syncthreads();
  for (int st = 128; st > 0; st >>= 1){
    if (tid < st) red[tid] += red[tid + st];
    __syncthreads();
  }
  const float inv = 1.f / red[0];
  float4* o4 = (float4*)(out + base);
  for (int i = tid; i < NN / 4; i += 256){
    float4 v = es4[i];
    v.x *= inv; v.y *= inv; v.z *= inv; v.w *= inv;
    o4[i] = v;
  }
}

extern "C" void kernel_launch(void* const* d_in, const int* in_sizes, int n_in,
                              void* d_out, int out_size, void* d_ws, size_t ws_size,
                              hipStream_t stream)
{
  const float* nodes = (const float*)d_in[0];
  const float* last  = (const float*)d_in[1];
  const float* q1    = (const float*)d_in[2];
  const float* q2    = (const float*)d_in[3];
  const float* loadv = (const float*)d_in[4];
  const float* leftv = (const float*)d_in[5];
  const float* dist  = (const float*)d_in[6];
  const float* ninf  = (const float*)d_in[7];
  const float* ls    = (const float*)d_in[8];
  const float* Wq1   = (const float*)d_in[9];
  const float* Wq2   = (const float*)d_in[10];
  const float* Wql   = (const float*)d_in[11];
  const float* Wk    = (const float*)d_in[12];
  const float* Wv    = (const float*)d_in[13];
  const float* aa    = (const float*)d_in[14];
  const float* pa    = (const float*)d_in[15];
  float* out = (float*)d_out;

  char* wsb = (char*)d_ws;
  float*    sq      = (float*)(wsb);                 // 1,638,400 B
  ushort_t* aft_bf  = (ushort_t*)(wsb + 1638400);    // 1,048,576 B
  ushort_t* ekkT    = (ushort_t*)(wsb + 2686976);    // 16,777,216 B [16][256][2048]
  ushort_t* nbf     = (ushort_t*)(wsb + 19464192);   //  8,388,608 B [16][2048][128]
  ushort_t* wbf     = (ushort_t*)(wsb + 27852800);   //     65,536 B [2][128][128]
  float*    partial = (float*)(wsb + 27918336);      // 16,777,216 B [4][16][256][256]
  float*    score   = partial;                       // 25,600,000 B (partial dead)

  k_qproj<<<dim3((BB * PP) / 8), dim3(128), 0, stream>>>(q1, q2, last, loadv, leftv, Wq1, Wq2, Wql, sq);
  k_prep_all<<<dim3(2064), dim3(256), 0, stream>>>(nodes, nbf, Wk, Wv, wbf);
  k_kv_mfma<<<dim3(16 * BB), dim3(512), 69632, stream>>>(nbf, wbf, ekkT);
  k_aft_mfma<<<dim3(32 * BB), dim3(256), 0, stream>>>(dist, ninf, ekkT, ls, aa, partial);
  k_aft_reduce<<<dim3(32, BB), dim3(256), 0, stream>>>(partial, sq, aft_bf);
  k_score_gemm<<<dim3(32 * BB), dim3(512), 0, stream>>>(aft_bf, nbf, score);
  k_scale_fused<<<dim3(PP, BB), dim3(256), 0, stream>>>(score, dist, ninf, ls, pa, out);
}